// Round 7
// baseline (799.150 us; speedup 1.0000x reference)
//
#include <hip/hip_runtime.h>

typedef unsigned int u32;
typedef unsigned short u16;
typedef __attribute__((ext_vector_type(8))) short bf16x8;
typedef __attribute__((ext_vector_type(4))) float f32x4;

__device__ __forceinline__ u16 f2b(float f){
  u32 x = __float_as_uint(f);
  u32 r = (x + 0x7fffu + ((x >> 16) & 1u)) >> 16;
  return (u16)r;
}
__device__ __forceinline__ float bl(u32 u){ return __uint_as_float(u << 16); }
__device__ __forceinline__ float bh(u32 u){ return __uint_as_float(u & 0xffff0000u); }

// ---------- preprocessing ----------

__global__ void k_detect(const u32* __restrict__ ei, int n, u32* __restrict__ flag){
  int t = blockIdx.x * blockDim.x + threadIdx.x;
  u32 v = 0;
  if (t < n) v = ei[2 * t + 1];
  unsigned long long b = __ballot(v != 0u);
  if ((threadIdx.x & 63) == 0 && b) atomicOr(flag, 1u);
}

// fused convert + histogram
__global__ void k_convhist(const int* __restrict__ ei, int* __restrict__ src, int* __restrict__ dst,
                           int* __restrict__ deg, int E, const u32* __restrict__ flag){
  int e = blockIdx.x * blockDim.x + threadIdx.x;
  if (e >= E) return;
  bool is64 = (*flag == 0u);
  int s, d;
  if (is64){ s = ei[2 * e]; d = ei[2 * (E + e)]; }
  else     { s = ei[e];     d = ei[E + e]; }
  src[e] = s; dst[e] = d;
  atomicAdd(&deg[d], 1);
}

// single-block shfl-based scan (exclusive), int4-vectorized, seg[n] = total
__global__ __launch_bounds__(1024) void k_scan(const int* __restrict__ deg, int* __restrict__ seg, int n){
  __shared__ int wsum[16];
  __shared__ int carry_s;
  int t = threadIdx.x, lane = t & 63, w = t >> 6;
  if (t == 0) carry_s = 0;
  __syncthreads();
  int n4 = (n + 3) >> 2;
  for (int base = 0; base < n4; base += 1024){
    int g = base + t;
    int i0 = g * 4;
    int4 v = make_int4(0, 0, 0, 0);
    if (g < n4){
      if (i0 + 3 < n) v = *(const int4*)(deg + i0);
      else {
        if (i0 < n)     v.x = deg[i0];
        if (i0 + 1 < n) v.y = deg[i0 + 1];
        if (i0 + 2 < n) v.z = deg[i0 + 2];
      }
    }
    int tot = v.x + v.y + v.z + v.w;
    int x = tot;
    #pragma unroll
    for (int off = 1; off < 64; off <<= 1){
      int y = __shfl_up(x, off);
      if (lane >= off) x += y;
    }
    if (lane == 63) wsum[w] = x;
    __syncthreads();
    if (w == 0 && lane < 16){
      int sv = wsum[lane];
      #pragma unroll
      for (int off = 1; off < 16; off <<= 1){
        int y = __shfl_up(sv, off);
        if (lane >= off) sv += y;
      }
      wsum[lane] = sv;
    }
    __syncthreads();
    int woff = (w > 0) ? wsum[w - 1] : 0;
    int carry = carry_s;
    int incl = carry + woff + x;
    int excl = incl - tot;
    if (i0 < n){
      seg[i0] = excl;
      if (i0 + 1 < n) seg[i0 + 1] = excl + v.x;
      if (i0 + 2 < n) seg[i0 + 2] = excl + v.x + v.y;
      if (i0 + 3 < n) seg[i0 + 3] = excl + v.x + v.y + v.z;
    }
    __syncthreads();
    if (t == 1023) carry_s = incl;
    __syncthreads();
  }
  if (threadIdx.x == 0) seg[n] = carry_s;
}

__global__ void k_scatter(const int* __restrict__ src, const int* __restrict__ dst,
                          const int* __restrict__ seg, int* __restrict__ cur,
                          int* __restrict__ ssrc, int* __restrict__ sdst,
                          int* __restrict__ seid, int E){
  int e = blockIdx.x * blockDim.x + threadIdx.x;
  if (e >= E) return;
  int d = dst[e];
  int pos = seg[d] + atomicAdd(&cur[d], 1);
  ssrc[pos] = src[e];
  sdst[pos] = d;
  seid[pos] = e;
}

// edge_attr in dst-sorted order as bf16
__global__ void k_sorte(const int* __restrict__ seid, const float* __restrict__ eattr,
                        u16* __restrict__ ea2, int E){
  int e = blockIdx.x * blockDim.x + threadIdx.x;
  if (e >= E) return;
  const float4* srow = (const float4*)(eattr + (size_t)seid[e] * 32);
  u32 pk[16];
  #pragma unroll
  for (int i = 0; i < 8; i++){
    float4 v = srow[i];
    pk[2*i]   = (u32)f2b(v.x) | ((u32)f2b(v.y) << 16);
    pk[2*i+1] = (u32)f2b(v.z) | ((u32)f2b(v.w) << 16);
  }
  uint4* drow = (uint4*)(ea2 + (size_t)e * 32);
  drow[0] = make_uint4(pk[0], pk[1], pk[2], pk[3]);
  drow[1] = make_uint4(pk[4], pk[5], pk[6], pk[7]);
  drow[2] = make_uint4(pk[8], pk[9], pk[10], pk[11]);
  drow[3] = make_uint4(pk[12], pk[13], pk[14], pk[15]);
}

// ---------- node transform: xl = A@Wl, xr = A@Wr (f32) + bf16 copies ----------
__global__ __launch_bounds__(256) void k_gemm(const float* __restrict__ A,
    const float* __restrict__ Wl, const float* __restrict__ Wr,
    float* __restrict__ xl, float* __restrict__ xr,
    u16* __restrict__ xlb, u16* __restrict__ xrb, int nrows)
{
  __shared__ float sA[32][128];
  __shared__ float sW[32][256];
  int t  = threadIdx.x;
  int rb = blockIdx.x * 32;

  #pragma unroll
  for (int i = 0; i < 4; i++){
    int f = t * 16 + i * 4;
    int r = f >> 7, c = f & 127;
    int gr = rb + r;
    float4 v = make_float4(0.f, 0.f, 0.f, 0.f);
    if (gr < nrows) v = *(const float4*)(A + (size_t)gr * 128 + c);
    *(float4*)&sA[r][c] = v;
  }

  int r0 = (t >> 5) * 4;
  int c0 = (t & 31) * 8;
  float acc[4][8];
  #pragma unroll
  for (int r = 0; r < 4; r++)
    #pragma unroll
    for (int j = 0; j < 8; j++) acc[r][j] = 0.f;

  for (int ko = 0; ko < 128; ko += 32){
    __syncthreads();
    #pragma unroll
    for (int i = 0; i < 8; i++){
      int q = i * 256 + t;
      int kl = q >> 6, c = (q & 63) * 4;
      float4 v;
      if (c < 128) v = *(const float4*)(Wl + (size_t)(ko + kl) * 128 + c);
      else         v = *(const float4*)(Wr + (size_t)(ko + kl) * 128 + (c - 128));
      *(float4*)&sW[kl][c] = v;
    }
    __syncthreads();
    #pragma unroll 4
    for (int kl = 0; kl < 32; kl++){
      int k = ko + kl;
      float a0 = sA[r0][k], a1 = sA[r0 + 1][k], a2 = sA[r0 + 2][k], a3 = sA[r0 + 3][k];
      float4 wA = *(float4*)&sW[kl][c0];
      float4 wB = *(float4*)&sW[kl][c0 + 4];
      float wv[8] = { wA.x, wA.y, wA.z, wA.w, wB.x, wB.y, wB.z, wB.w };
      #pragma unroll
      for (int j = 0; j < 8; j++){
        acc[0][j] = fmaf(a0, wv[j], acc[0][j]);
        acc[1][j] = fmaf(a1, wv[j], acc[1][j]);
        acc[2][j] = fmaf(a2, wv[j], acc[2][j]);
        acc[3][j] = fmaf(a3, wv[j], acc[3][j]);
      }
    }
  }

  float* outp = (c0 < 128) ? xl : xr;
  u16*   outb = (c0 < 128) ? xlb : xrb;
  int cc = c0 & 127;
  #pragma unroll
  for (int r = 0; r < 4; r++){
    int gr = rb + r0 + r;
    if (gr < nrows){
      *(float4*)(outp + (size_t)gr * 128 + cc)     = make_float4(acc[r][0], acc[r][1], acc[r][2], acc[r][3]);
      *(float4*)(outp + (size_t)gr * 128 + cc + 4) = make_float4(acc[r][4], acc[r][5], acc[r][6], acc[r][7]);
      uint4 pk;
      pk.x = (u32)f2b(acc[r][0]) | ((u32)f2b(acc[r][1]) << 16);
      pk.y = (u32)f2b(acc[r][2]) | ((u32)f2b(acc[r][3]) << 16);
      pk.z = (u32)f2b(acc[r][4]) | ((u32)f2b(acc[r][5]) << 16);
      pk.w = (u32)f2b(acc[r][6]) | ((u32)f2b(acc[r][7]) << 16);
      *(uint4*)(outb + (size_t)gr * 128 + cc) = pk;
    }
  }
}

// ---------- edge kernel: MFMA ea@We + LDS bounce + thread-per-edge epilogue ----------
__global__ __launch_bounds__(256) void k_edge(
    const int* __restrict__ ssrc, const int* __restrict__ sdst,
    const u16* __restrict__ ea2,
    const u16* __restrict__ xlb, const u16* __restrict__ xrb,
    const float* __restrict__ We, const float* __restrict__ att,
    float2* __restrict__ pr2, int ntiles, int E)
{
  __shared__ float sD[4][16][136];
  int wv = threadIdx.x >> 6, lane = threadIdx.x & 63;
  int col = lane & 15, kg = lane >> 4;
  int er = lane >> 2, q = lane & 3;

  bf16x8 bw[8];
  #pragma unroll
  for (int c = 0; c < 8; c++)
    #pragma unroll
    for (int j = 0; j < 8; j++)
      bw[c][j] = (short)f2b(We[(kg * 8 + j) * 128 + c * 16 + col]);
  float attq[32];
  #pragma unroll
  for (int i = 0; i < 8; i++){
    float4 a4 = *(const float4*)(att + q * 32 + i * 4);
    attq[4*i] = a4.x; attq[4*i+1] = a4.y; attq[4*i+2] = a4.z; attq[4*i+3] = a4.w;
  }

  int wid0 = blockIdx.x * 4 + wv;
  int nw = gridDim.x * 4;
  for (int t = wid0; t < ntiles; t += nw){
    int e0 = t * 16;
    bf16x8 a = *(const bf16x8*)(ea2 + (size_t)(e0 + col) * 32 + kg * 8);
    #pragma unroll
    for (int c = 0; c < 8; c++){
      f32x4 d = __builtin_amdgcn_mfma_f32_16x16x32_bf16(a, bw[c], (f32x4){0.f,0.f,0.f,0.f}, 0, 0, 0);
      #pragma unroll
      for (int r = 0; r < 4; r++)
        sD[wv][kg * 4 + r][c * 16 + col] = d[r];
    }
    int p = e0 + er;
    int sn = ssrc[p], dn = sdst[p];
    const u16* xj = xlb + (size_t)sn * 128 + q * 32;
    const u16* xi = xrb + (size_t)dn * 128 + q * 32;
    uint4 jq[4], iq[4];
    jq[0] = *(const uint4*)(xj);      jq[1] = *(const uint4*)(xj + 8);
    jq[2] = *(const uint4*)(xj + 16); jq[3] = *(const uint4*)(xj + 24);
    iq[0] = *(const uint4*)(xi);      iq[1] = *(const uint4*)(xi + 8);
    iq[2] = *(const uint4*)(xi + 16); iq[3] = *(const uint4*)(xi + 24);
    const float* drow = &sD[wv][er][q * 32];

    float acc = 0.f;
    #pragma unroll
    for (int k = 0; k < 4; k++){
      float4 d0 = *(const float4*)(drow + k * 8);
      float4 d1 = *(const float4*)(drow + k * 8 + 4);
      u32 jw[4] = { jq[k].x, jq[k].y, jq[k].z, jq[k].w };
      u32 iw[4] = { iq[k].x, iq[k].y, iq[k].z, iq[k].w };
      float dv[8] = { d0.x, d0.y, d0.z, d0.w, d1.x, d1.y, d1.z, d1.w };
      #pragma unroll
      for (int m = 0; m < 4; m++){
        float v0 = dv[2*m]   + bl(jw[m]) + bl(iw[m]);
        float v1 = dv[2*m+1] + bh(jw[m]) + bh(iw[m]);
        v0 = fmaxf(v0, 0.2f * v0);
        v1 = fmaxf(v1, 0.2f * v1);
        acc = fmaf(v0, attq[k*8 + 2*m], acc);
        acc = fmaf(v1, attq[k*8 + 2*m + 1], acc);
      }
    }
    acc += __shfl_xor(acc, 1);
    float other = __shfl_xor(acc, 2);
    if (q == 0 && p < E){
      float l0 = fminf(acc, 80.f), l1 = fminf(other, 80.f);
      pr2[p] = make_float2(__expf(l0), __expf(l1));
    }
  }
}

// ---------- per-node reduce, 8-wide ILP: sum + weighted sum + epilogue ----------
template<int RELU>
__global__ __launch_bounds__(256) void k_seg2(
    const int* __restrict__ seg, const int* __restrict__ ssrc,
    const float2* __restrict__ pr2,
    const float* __restrict__ xl, const float* __restrict__ bias,
    float* __restrict__ out, int N)
{
  int wid  = blockIdx.x * 4 + (threadIdx.x >> 6);
  int lane = threadIdx.x & 63;
  if (wid >= N) return;
  int c0 = lane * 2, head = lane >> 5;

  int p0 = seg[wid], p1 = seg[wid + 1];
  float2 bv = *(const float2*)(bias + c0);
  float s = 0.f, o0 = 0.f, o1 = 0.f;

  for (int p = p0; p < p1; p += 8){
    int rem = p1 - p;
    int idx[8];
    #pragma unroll
    for (int k = 0; k < 8; k++) idx[k] = (k < rem) ? (p + k) : p;
    int sn[8];
    #pragma unroll
    for (int k = 0; k < 8; k++) sn[k] = ssrc[idx[k]];
    float2 q[8];
    #pragma unroll
    for (int k = 0; k < 8; k++) q[k] = pr2[idx[k]];
    float2 xv[8];
    #pragma unroll
    for (int k = 0; k < 8; k++) xv[k] = *(const float2*)(xl + (size_t)sn[k] * 128 + c0);
    #pragma unroll
    for (int k = 0; k < 8; k++){
      float e = head ? q[k].y : q[k].x;
      e = (k < rem) ? e : 0.f;
      s += e;
      o0 = fmaf(e, xv[k].x, o0);
      o1 = fmaf(e, xv[k].y, o1);
    }
  }
  float inv = 1.0f / (s + 1e-16f);
  float r0 = fmaf(o0, inv, bv.x);
  float r1 = fmaf(o1, inv, bv.y);
  if (RELU){ r0 = fmaxf(r0, 0.f); r1 = fmaxf(r1, 0.f); }
  *(float2*)(out + (size_t)wid * 128 + c0) = make_float2(r0, r1);
}

// ---------- launch ----------
extern "C" void kernel_launch(void* const* d_in, const int* in_sizes, int n_in,
                              void* d_out, int out_size, void* d_ws, size_t ws_size,
                              hipStream_t stream)
{
  const float* x     = (const float*)d_in[0];
  const int*   ei    = (const int*)  d_in[1];
  const float* eattr = (const float*)d_in[2];
  const float* Wp[3][5];
  for (int l = 0; l < 3; l++)
    for (int j = 0; j < 5; j++)
      Wp[l][j] = (const float*)d_in[3 + l * 5 + j];

  int N = in_sizes[0] / 128;
  int E = in_sizes[2] / 32;

  char* w = (char*)d_ws;
  auto alloc = [&](size_t bytes) -> char* {
    char* p = w; w += (bytes + 255) & ~(size_t)255; return p;
  };
  float* xl   = (float*)alloc((size_t)N * 128 * 4);
  float* xr   = (float*)alloc((size_t)N * 128 * 4);   // also inter-layer h buffer
  u16*   xlb  = (u16*)  alloc((size_t)N * 128 * 2);
  u16*   xrb  = (u16*)  alloc((size_t)N * 128 * 2);
  u16*   ea2  = (u16*)  alloc((size_t)(E + 64) * 32 * 2);
  float2* prb = (float2*)alloc((size_t)E * 8);
  int* srcA   = (int*)alloc((size_t)E * 4);
  int* dstA   = (int*)alloc((size_t)E * 4);
  int* ssrc   = (int*)alloc((size_t)(E + 64) * 4);
  int* sdst   = (int*)alloc((size_t)(E + 64) * 4);
  int* seid   = (int*)alloc((size_t)E * 4);
  int* deg    = (int*)alloc((size_t)N * 4);
  int* cur    = (int*)alloc((size_t)N * 4);
  int* seg    = (int*)alloc((size_t)(N + 1) * 4);
  u32* flag   = (u32*)alloc(256);

  hipMemsetAsync(deg,  0, (size_t)N * 4, stream);
  hipMemsetAsync(cur,  0, (size_t)N * 4, stream);
  hipMemsetAsync(flag, 0, 4, stream);
  hipMemsetAsync(ssrc + E, 0, 64 * 4, stream);
  hipMemsetAsync(sdst + E, 0, 64 * 4, stream);

  int ndet = (E < 16384) ? E : 16384;
  k_detect<<<(ndet + 255) / 256, 256, 0, stream>>>((const u32*)ei, ndet, flag);
  int gE = (E + 255) / 256;
  k_convhist<<<gE, 256, 0, stream>>>(ei, srcA, dstA, deg, E, flag);
  k_scan<<<1, 1024, 0, stream>>>(deg, seg, N);
  k_scatter<<<gE, 256, 0, stream>>>(srcA, dstA, seg, cur, ssrc, sdst, seid, E);
  k_sorte<<<gE, 256, 0, stream>>>(seid, eattr, ea2, E);

  int gG = (N + 31) / 32;
  int gS = (N + 3) / 4;
  int ntiles = (E + 15) / 16;
  int gEdge = (ntiles + 3) / 4; if (gEdge > 2048) gEdge = 2048;

  const float* hin = x;
  for (int l = 0; l < 3; l++){
    k_gemm<<<gG, 256, 0, stream>>>(hin, Wp[l][0], Wp[l][1], xl, xr, xlb, xrb, N);
    k_edge<<<gEdge, 256, 0, stream>>>(ssrc, sdst, ea2, xlb, xrb, Wp[l][2], Wp[l][3], prb, ntiles, E);
    float* outp = (l == 2) ? (float*)d_out : xr;
    if (l == 2) k_seg2<0><<<gS, 256, 0, stream>>>(seg, ssrc, prb, xl, Wp[l][4], outp, N);
    else        k_seg2<1><<<gS, 256, 0, stream>>>(seg, ssrc, prb, xl, Wp[l][4], outp, N);
    hin = xr;
  }
}

// Round 8
// 635.079 us; speedup vs baseline: 1.2583x; 1.2583x over previous
//
#include <hip/hip_runtime.h>

typedef unsigned int u32;
typedef unsigned short u16;
typedef __attribute__((ext_vector_type(8))) short bf16x8;
typedef __attribute__((ext_vector_type(4))) float f32x4;

__device__ __forceinline__ u16 f2b(float f){
  u32 x = __float_as_uint(f);
  u32 r = (x + 0x7fffu + ((x >> 16) & 1u)) >> 16;
  return (u16)r;
}
__device__ __forceinline__ float bl(u32 u){ return __uint_as_float(u << 16); }
__device__ __forceinline__ float bh(u32 u){ return __uint_as_float(u & 0xffff0000u); }

// ---------- preprocessing ----------

__global__ void k_detect(const u32* __restrict__ ei, int n, u32* __restrict__ flag){
  int t = blockIdx.x * blockDim.x + threadIdx.x;
  u32 v = 0;
  if (t < n) v = ei[2 * t + 1];
  unsigned long long b = __ballot(v != 0u);
  if ((threadIdx.x & 63) == 0 && b) atomicOr(flag, 1u);
}

// fused convert + histogram
__global__ void k_convhist(const int* __restrict__ ei, int* __restrict__ src, int* __restrict__ dst,
                           int* __restrict__ deg, int E, const u32* __restrict__ flag){
  int e = blockIdx.x * blockDim.x + threadIdx.x;
  if (e >= E) return;
  bool is64 = (*flag == 0u);
  int s, d;
  if (is64){ s = ei[2 * e]; d = ei[2 * (E + e)]; }
  else     { s = ei[e];     d = ei[E + e]; }
  src[e] = s; dst[e] = d;
  atomicAdd(&deg[d], 1);
}

// single-block shfl-based scan (exclusive), int4-vectorized, seg[n] = total
__global__ __launch_bounds__(1024) void k_scan(const int* __restrict__ deg, int* __restrict__ seg, int n){
  __shared__ int wsum[16];
  __shared__ int carry_s;
  int t = threadIdx.x, lane = t & 63, w = t >> 6;
  if (t == 0) carry_s = 0;
  __syncthreads();
  int n4 = (n + 3) >> 2;
  for (int base = 0; base < n4; base += 1024){
    int g = base + t;
    int i0 = g * 4;
    int4 v = make_int4(0, 0, 0, 0);
    if (g < n4){
      if (i0 + 3 < n) v = *(const int4*)(deg + i0);
      else {
        if (i0 < n)     v.x = deg[i0];
        if (i0 + 1 < n) v.y = deg[i0 + 1];
        if (i0 + 2 < n) v.z = deg[i0 + 2];
      }
    }
    int tot = v.x + v.y + v.z + v.w;
    int x = tot;
    #pragma unroll
    for (int off = 1; off < 64; off <<= 1){
      int y = __shfl_up(x, off);
      if (lane >= off) x += y;
    }
    if (lane == 63) wsum[w] = x;
    __syncthreads();
    if (w == 0 && lane < 16){
      int sv = wsum[lane];
      #pragma unroll
      for (int off = 1; off < 16; off <<= 1){
        int y = __shfl_up(sv, off);
        if (lane >= off) sv += y;
      }
      wsum[lane] = sv;
    }
    __syncthreads();
    int woff = (w > 0) ? wsum[w - 1] : 0;
    int carry = carry_s;
    int incl = carry + woff + x;
    int excl = incl - tot;
    if (i0 < n){
      seg[i0] = excl;
      if (i0 + 1 < n) seg[i0 + 1] = excl + v.x;
      if (i0 + 2 < n) seg[i0 + 2] = excl + v.x + v.y;
      if (i0 + 3 < n) seg[i0 + 3] = excl + v.x + v.y + v.z;
    }
    __syncthreads();
    if (t == 1023) carry_s = incl;
    __syncthreads();
  }
  if (threadIdx.x == 0) seg[n] = carry_s;
}

__global__ void k_scatter(const int* __restrict__ src, const int* __restrict__ dst,
                          const int* __restrict__ seg, int* __restrict__ cur,
                          int* __restrict__ ssrc, int* __restrict__ sdst,
                          int* __restrict__ seid, int E){
  int e = blockIdx.x * blockDim.x + threadIdx.x;
  if (e >= E) return;
  int d = dst[e];
  int pos = seg[d] + atomicAdd(&cur[d], 1);
  ssrc[pos] = src[e];
  sdst[pos] = d;
  seid[pos] = e;
}

// edge_attr in dst-sorted order as bf16
__global__ void k_sorte(const int* __restrict__ seid, const float* __restrict__ eattr,
                        u16* __restrict__ ea2, int E){
  int e = blockIdx.x * blockDim.x + threadIdx.x;
  if (e >= E) return;
  const float4* srow = (const float4*)(eattr + (size_t)seid[e] * 32);
  u32 pk[16];
  #pragma unroll
  for (int i = 0; i < 8; i++){
    float4 v = srow[i];
    pk[2*i]   = (u32)f2b(v.x) | ((u32)f2b(v.y) << 16);
    pk[2*i+1] = (u32)f2b(v.z) | ((u32)f2b(v.w) << 16);
  }
  uint4* drow = (uint4*)(ea2 + (size_t)e * 32);
  drow[0] = make_uint4(pk[0], pk[1], pk[2], pk[3]);
  drow[1] = make_uint4(pk[4], pk[5], pk[6], pk[7]);
  drow[2] = make_uint4(pk[8], pk[9], pk[10], pk[11]);
  drow[3] = make_uint4(pk[12], pk[13], pk[14], pk[15]);
}

// ---------- node transform: h@Wl -> xlb (bf16), h@Wr -> xr (f32) + xrb (bf16) ----------
__global__ __launch_bounds__(256) void k_gemm(const float* __restrict__ A,
    const float* __restrict__ Wl, const float* __restrict__ Wr,
    float* __restrict__ xr,
    u16* __restrict__ xlb, u16* __restrict__ xrb, int nrows)
{
  __shared__ float sA[32][128];
  __shared__ float sW[32][256];
  int t  = threadIdx.x;
  int rb = blockIdx.x * 32;

  #pragma unroll
  for (int i = 0; i < 4; i++){
    int f = t * 16 + i * 4;
    int r = f >> 7, c = f & 127;
    int gr = rb + r;
    float4 v = make_float4(0.f, 0.f, 0.f, 0.f);
    if (gr < nrows) v = *(const float4*)(A + (size_t)gr * 128 + c);
    *(float4*)&sA[r][c] = v;
  }

  int r0 = (t >> 5) * 4;
  int c0 = (t & 31) * 8;
  float acc[4][8];
  #pragma unroll
  for (int r = 0; r < 4; r++)
    #pragma unroll
    for (int j = 0; j < 8; j++) acc[r][j] = 0.f;

  for (int ko = 0; ko < 128; ko += 32){
    __syncthreads();
    #pragma unroll
    for (int i = 0; i < 8; i++){
      int q = i * 256 + t;
      int kl = q >> 6, c = (q & 63) * 4;
      float4 v;
      if (c < 128) v = *(const float4*)(Wl + (size_t)(ko + kl) * 128 + c);
      else         v = *(const float4*)(Wr + (size_t)(ko + kl) * 128 + (c - 128));
      *(float4*)&sW[kl][c] = v;
    }
    __syncthreads();
    #pragma unroll 4
    for (int kl = 0; kl < 32; kl++){
      int k = ko + kl;
      float a0 = sA[r0][k], a1 = sA[r0 + 1][k], a2 = sA[r0 + 2][k], a3 = sA[r0 + 3][k];
      float4 wA = *(float4*)&sW[kl][c0];
      float4 wB = *(float4*)&sW[kl][c0 + 4];
      float wv[8] = { wA.x, wA.y, wA.z, wA.w, wB.x, wB.y, wB.z, wB.w };
      #pragma unroll
      for (int j = 0; j < 8; j++){
        acc[0][j] = fmaf(a0, wv[j], acc[0][j]);
        acc[1][j] = fmaf(a1, wv[j], acc[1][j]);
        acc[2][j] = fmaf(a2, wv[j], acc[2][j]);
        acc[3][j] = fmaf(a3, wv[j], acc[3][j]);
      }
    }
  }

  bool left = (c0 < 128);
  u16* outb = left ? xlb : xrb;
  int cc = c0 & 127;
  #pragma unroll
  for (int r = 0; r < 4; r++){
    int gr = rb + r0 + r;
    if (gr < nrows){
      if (!left){
        *(float4*)(xr + (size_t)gr * 128 + cc)     = make_float4(acc[r][0], acc[r][1], acc[r][2], acc[r][3]);
        *(float4*)(xr + (size_t)gr * 128 + cc + 4) = make_float4(acc[r][4], acc[r][5], acc[r][6], acc[r][7]);
      }
      uint4 pk;
      pk.x = (u32)f2b(acc[r][0]) | ((u32)f2b(acc[r][1]) << 16);
      pk.y = (u32)f2b(acc[r][2]) | ((u32)f2b(acc[r][3]) << 16);
      pk.z = (u32)f2b(acc[r][4]) | ((u32)f2b(acc[r][5]) << 16);
      pk.w = (u32)f2b(acc[r][6]) | ((u32)f2b(acc[r][7]) << 16);
      *(uint4*)(outb + (size_t)gr * 128 + cc) = pk;
    }
  }
}

// ---------- edge kernel: MFMA ea@We + LDS bounce + thread-per-edge epilogue ----------
__global__ __launch_bounds__(256) void k_edge(
    const int* __restrict__ ssrc, const int* __restrict__ sdst,
    const u16* __restrict__ ea2,
    const u16* __restrict__ xlb, const u16* __restrict__ xrb,
    const float* __restrict__ We, const float* __restrict__ att,
    float2* __restrict__ pr2, int ntiles, int E)
{
  __shared__ float sD[4][16][136];
  int wv = threadIdx.x >> 6, lane = threadIdx.x & 63;
  int col = lane & 15, kg = lane >> 4;
  int er = lane >> 2, q = lane & 3;

  bf16x8 bw[8];
  #pragma unroll
  for (int c = 0; c < 8; c++)
    #pragma unroll
    for (int j = 0; j < 8; j++)
      bw[c][j] = (short)f2b(We[(kg * 8 + j) * 128 + c * 16 + col]);
  float attq[32];
  #pragma unroll
  for (int i = 0; i < 8; i++){
    float4 a4 = *(const float4*)(att + q * 32 + i * 4);
    attq[4*i] = a4.x; attq[4*i+1] = a4.y; attq[4*i+2] = a4.z; attq[4*i+3] = a4.w;
  }

  int wid0 = blockIdx.x * 4 + wv;
  int nw = gridDim.x * 4;
  for (int t = wid0; t < ntiles; t += nw){
    int e0 = t * 16;
    bf16x8 a = *(const bf16x8*)(ea2 + (size_t)(e0 + col) * 32 + kg * 8);
    #pragma unroll
    for (int c = 0; c < 8; c++){
      f32x4 d = __builtin_amdgcn_mfma_f32_16x16x32_bf16(a, bw[c], (f32x4){0.f,0.f,0.f,0.f}, 0, 0, 0);
      #pragma unroll
      for (int r = 0; r < 4; r++)
        sD[wv][kg * 4 + r][c * 16 + col] = d[r];
    }
    int p = e0 + er;
    int sn = ssrc[p], dn = sdst[p];
    const u16* xj = xlb + (size_t)sn * 128 + q * 32;
    const u16* xi = xrb + (size_t)dn * 128 + q * 32;
    uint4 jq[4], iq[4];
    jq[0] = *(const uint4*)(xj);      jq[1] = *(const uint4*)(xj + 8);
    jq[2] = *(const uint4*)(xj + 16); jq[3] = *(const uint4*)(xj + 24);
    iq[0] = *(const uint4*)(xi);      iq[1] = *(const uint4*)(xi + 8);
    iq[2] = *(const uint4*)(xi + 16); iq[3] = *(const uint4*)(xi + 24);
    const float* drow = &sD[wv][er][q * 32];

    float acc = 0.f;
    #pragma unroll
    for (int k = 0; k < 4; k++){
      float4 d0 = *(const float4*)(drow + k * 8);
      float4 d1 = *(const float4*)(drow + k * 8 + 4);
      u32 jw[4] = { jq[k].x, jq[k].y, jq[k].z, jq[k].w };
      u32 iw[4] = { iq[k].x, iq[k].y, iq[k].z, iq[k].w };
      float dv[8] = { d0.x, d0.y, d0.z, d0.w, d1.x, d1.y, d1.z, d1.w };
      #pragma unroll
      for (int m = 0; m < 4; m++){
        float v0 = dv[2*m]   + bl(jw[m]) + bl(iw[m]);
        float v1 = dv[2*m+1] + bh(jw[m]) + bh(iw[m]);
        v0 = fmaxf(v0, 0.2f * v0);
        v1 = fmaxf(v1, 0.2f * v1);
        acc = fmaf(v0, attq[k*8 + 2*m], acc);
        acc = fmaf(v1, attq[k*8 + 2*m + 1], acc);
      }
    }
    acc += __shfl_xor(acc, 1);
    float other = __shfl_xor(acc, 2);
    if (q == 0 && p < E){
      float l0 = fminf(acc, 80.f), l1 = fminf(other, 80.f);
      pr2[p] = make_float2(__expf(l0), __expf(l1));
    }
  }
}

// ---------- per-node reduce, 8-deep NAMED-scalar pipeline, bf16 gathers ----------
template<int RELU>
__global__ __launch_bounds__(256) void k_seg2(
    const int* __restrict__ seg, const int* __restrict__ ssrc,
    const float2* __restrict__ pr2,
    const u16* __restrict__ xlb, const float* __restrict__ bias,
    float* __restrict__ out, int N)
{
  int wid  = blockIdx.x * 4 + (threadIdx.x >> 6);
  int lane = threadIdx.x & 63;
  if (wid >= N) return;
  int c0 = lane * 2, head = lane >> 5;

  int p0 = seg[wid], p1 = seg[wid + 1];
  float2 bv = *(const float2*)(bias + c0);
  float s = 0.f, o0 = 0.f, o1 = 0.f;

  for (int p = p0; p < p1; p += 8){
#define STAGE(K) \
    int i##K = (p + K < p1) ? (p + K) : (p1 - 1); \
    int sn##K = ssrc[i##K]; \
    float2 q##K = pr2[i##K]; \
    u32 xv##K = *(const u32*)(xlb + (size_t)sn##K * 128 + c0);
    STAGE(0) STAGE(1) STAGE(2) STAGE(3) STAGE(4) STAGE(5) STAGE(6) STAGE(7)
#undef STAGE
#define ACCUM(K) { \
    float e##K = head ? q##K.y : q##K.x; \
    if (p + K >= p1) e##K = 0.f; \
    s += e##K; \
    o0 = fmaf(e##K, bl(xv##K), o0); \
    o1 = fmaf(e##K, bh(xv##K), o1); }
    ACCUM(0) ACCUM(1) ACCUM(2) ACCUM(3) ACCUM(4) ACCUM(5) ACCUM(6) ACCUM(7)
#undef ACCUM
  }
  float inv = 1.0f / (s + 1e-16f);
  float r0 = fmaf(o0, inv, bv.x);
  float r1 = fmaf(o1, inv, bv.y);
  if (RELU){ r0 = fmaxf(r0, 0.f); r1 = fmaxf(r1, 0.f); }
  *(float2*)(out + (size_t)wid * 128 + c0) = make_float2(r0, r1);
}

// ---------- launch ----------
extern "C" void kernel_launch(void* const* d_in, const int* in_sizes, int n_in,
                              void* d_out, int out_size, void* d_ws, size_t ws_size,
                              hipStream_t stream)
{
  const float* x     = (const float*)d_in[0];
  const int*   ei    = (const int*)  d_in[1];
  const float* eattr = (const float*)d_in[2];
  const float* Wp[3][5];
  for (int l = 0; l < 3; l++)
    for (int j = 0; j < 5; j++)
      Wp[l][j] = (const float*)d_in[3 + l * 5 + j];

  int N = in_sizes[0] / 128;
  int E = in_sizes[2] / 32;

  char* w = (char*)d_ws;
  auto alloc = [&](size_t bytes) -> char* {
    char* p = w; w += (bytes + 255) & ~(size_t)255; return p;
  };
  float* xr   = (float*)alloc((size_t)N * 128 * 4);   // also inter-layer h buffer
  u16*   xlb  = (u16*)  alloc((size_t)N * 128 * 2);
  u16*   xrb  = (u16*)  alloc((size_t)N * 128 * 2);
  u16*   ea2  = (u16*)  alloc((size_t)(E + 64) * 32 * 2);
  float2* prb = (float2*)alloc((size_t)E * 8);
  int* srcA   = (int*)alloc((size_t)E * 4);
  int* dstA   = (int*)alloc((size_t)E * 4);
  int* ssrc   = (int*)alloc((size_t)(E + 64) * 4);
  int* sdst   = (int*)alloc((size_t)(E + 64) * 4);
  int* seid   = (int*)alloc((size_t)E * 4);
  int* deg    = (int*)alloc((size_t)N * 4);
  int* cur    = (int*)alloc((size_t)N * 4);
  int* seg    = (int*)alloc((size_t)(N + 1) * 4);
  u32* flag   = (u32*)alloc(256);

  hipMemsetAsync(deg,  0, (size_t)N * 4, stream);
  hipMemsetAsync(cur,  0, (size_t)N * 4, stream);
  hipMemsetAsync(flag, 0, 4, stream);
  hipMemsetAsync(ssrc + E, 0, 64 * 4, stream);
  hipMemsetAsync(sdst + E, 0, 64 * 4, stream);

  int ndet = (E < 16384) ? E : 16384;
  k_detect<<<(ndet + 255) / 256, 256, 0, stream>>>((const u32*)ei, ndet, flag);
  int gE = (E + 255) / 256;
  k_convhist<<<gE, 256, 0, stream>>>(ei, srcA, dstA, deg, E, flag);
  k_scan<<<1, 1024, 0, stream>>>(deg, seg, N);
  k_scatter<<<gE, 256, 0, stream>>>(srcA, dstA, seg, cur, ssrc, sdst, seid, E);
  k_sorte<<<gE, 256, 0, stream>>>(seid, eattr, ea2, E);

  int gG = (N + 31) / 32;
  int gS = (N + 3) / 4;
  int ntiles = (E + 15) / 16;
  int gEdge = (ntiles + 3) / 4; if (gEdge > 2048) gEdge = 2048;

  const float* hin = x;
  for (int l = 0; l < 3; l++){
    k_gemm<<<gG, 256, 0, stream>>>(hin, Wp[l][0], Wp[l][1], xr, xlb, xrb, N);
    k_edge<<<gEdge, 256, 0, stream>>>(ssrc, sdst, ea2, xlb, xrb, Wp[l][2], Wp[l][3], prb, ntiles, E);
    float* outp = (l == 2) ? (float*)d_out : xr;
    if (l == 2) k_seg2<0><<<gS, 256, 0, stream>>>(seg, ssrc, prb, xlb, Wp[l][4], outp, N);
    else        k_seg2<1><<<gS, 256, 0, stream>>>(seg, ssrc, prb, xlb, Wp[l][4], outp, N);
    hin = xr;
  }
}

// Round 9
// 537.451 us; speedup vs baseline: 1.4869x; 1.1817x over previous
//
#include <hip/hip_runtime.h>

typedef unsigned int u32;
typedef unsigned short u16;
typedef __attribute__((ext_vector_type(8))) short bf16x8;
typedef __attribute__((ext_vector_type(4))) float f32x4;

__device__ __forceinline__ u16 f2b(float f){
  u32 x = __float_as_uint(f);
  u32 r = (x + 0x7fffu + ((x >> 16) & 1u)) >> 16;
  return (u16)r;
}
__device__ __forceinline__ float b2f(u16 h){ return __uint_as_float((u32)h << 16); }
__device__ __forceinline__ float bl(u32 u){ return __uint_as_float(u << 16); }
__device__ __forceinline__ float bh(u32 u){ return __uint_as_float(u & 0xffff0000u); }

// ---------- preprocessing ----------

__global__ void k_detect(const u32* __restrict__ ei, int n, u32* __restrict__ flag){
  int t = blockIdx.x * blockDim.x + threadIdx.x;
  u32 v = 0;
  if (t < n) v = ei[2 * t + 1];
  unsigned long long b = __ballot(v != 0u);
  if ((threadIdx.x & 63) == 0 && b) atomicOr(flag, 1u);
}

__global__ void k_convhist(const int* __restrict__ ei, int* __restrict__ src, int* __restrict__ dst,
                           int* __restrict__ deg, int E, const u32* __restrict__ flag){
  int e = blockIdx.x * blockDim.x + threadIdx.x;
  if (e >= E) return;
  bool is64 = (*flag == 0u);
  int s, d;
  if (is64){ s = ei[2 * e]; d = ei[2 * (E + e)]; }
  else     { s = ei[e];     d = ei[E + e]; }
  src[e] = s; dst[e] = d;
  atomicAdd(&deg[d], 1);
}

__global__ __launch_bounds__(1024) void k_scan(const int* __restrict__ deg, int* __restrict__ seg, int n){
  __shared__ int wsum[16];
  __shared__ int carry_s;
  int t = threadIdx.x, lane = t & 63, w = t >> 6;
  if (t == 0) carry_s = 0;
  __syncthreads();
  int n4 = (n + 3) >> 2;
  for (int base = 0; base < n4; base += 1024){
    int g = base + t;
    int i0 = g * 4;
    int4 v = make_int4(0, 0, 0, 0);
    if (g < n4){
      if (i0 + 3 < n) v = *(const int4*)(deg + i0);
      else {
        if (i0 < n)     v.x = deg[i0];
        if (i0 + 1 < n) v.y = deg[i0 + 1];
        if (i0 + 2 < n) v.z = deg[i0 + 2];
      }
    }
    int tot = v.x + v.y + v.z + v.w;
    int x = tot;
    #pragma unroll
    for (int off = 1; off < 64; off <<= 1){
      int y = __shfl_up(x, off);
      if (lane >= off) x += y;
    }
    if (lane == 63) wsum[w] = x;
    __syncthreads();
    if (w == 0 && lane < 16){
      int sv = wsum[lane];
      #pragma unroll
      for (int off = 1; off < 16; off <<= 1){
        int y = __shfl_up(sv, off);
        if (lane >= off) sv += y;
      }
      wsum[lane] = sv;
    }
    __syncthreads();
    int woff = (w > 0) ? wsum[w - 1] : 0;
    int carry = carry_s;
    int incl = carry + woff + x;
    int excl = incl - tot;
    if (i0 < n){
      seg[i0] = excl;
      if (i0 + 1 < n) seg[i0 + 1] = excl + v.x;
      if (i0 + 2 < n) seg[i0 + 2] = excl + v.x + v.y;
      if (i0 + 3 < n) seg[i0 + 3] = excl + v.x + v.y + v.z;
    }
    __syncthreads();
    if (t == 1023) carry_s = incl;
    __syncthreads();
  }
  if (threadIdx.x == 0) seg[n] = carry_s;
}

__global__ void k_scatter(const int* __restrict__ src, const int* __restrict__ dst,
                          const int* __restrict__ seg, int* __restrict__ cur,
                          int* __restrict__ ssrc, int* __restrict__ sdst,
                          int* __restrict__ seid, int E){
  int e = blockIdx.x * blockDim.x + threadIdx.x;
  if (e >= E) return;
  int d = dst[e];
  int pos = seg[d] + atomicAdd(&cur[d], 1);
  ssrc[pos] = src[e];
  sdst[pos] = d;
  seid[pos] = e;
}

__global__ void k_sorte(const int* __restrict__ seid, const float* __restrict__ eattr,
                        u16* __restrict__ ea2, int E){
  int e = blockIdx.x * blockDim.x + threadIdx.x;
  if (e >= E) return;
  const float4* srow = (const float4*)(eattr + (size_t)seid[e] * 32);
  u32 pk[16];
  #pragma unroll
  for (int i = 0; i < 8; i++){
    float4 v = srow[i];
    pk[2*i]   = (u32)f2b(v.x) | ((u32)f2b(v.y) << 16);
    pk[2*i+1] = (u32)f2b(v.z) | ((u32)f2b(v.w) << 16);
  }
  uint4* drow = (uint4*)(ea2 + (size_t)e * 32);
  drow[0] = make_uint4(pk[0], pk[1], pk[2], pk[3]);
  drow[1] = make_uint4(pk[4], pk[5], pk[6], pk[7]);
  drow[2] = make_uint4(pk[8], pk[9], pk[10], pk[11]);
  drow[3] = make_uint4(pk[12], pk[13], pk[14], pk[15]);
}

// ---------- W prep: transpose + bf16 hi/lo split; 6 matrices [128k][128c] -> [mat][c][k] ----------
__global__ __launch_bounds__(256) void k_prepw(
    const float* __restrict__ W0, const float* __restrict__ W1, const float* __restrict__ W2,
    const float* __restrict__ W3, const float* __restrict__ W4, const float* __restrict__ W5,
    u16* __restrict__ WtH, u16* __restrict__ WtL)
{
  int mat = blockIdx.z;
  const float* W = (mat == 0) ? W0 : (mat == 1) ? W1 : (mat == 2) ? W2 :
                   (mat == 3) ? W3 : (mat == 4) ? W4 : W5;
  __shared__ float tile[32][33];
  int kt = blockIdx.x * 32, ct = blockIdx.y * 32;
  int tr = threadIdx.x & 31, ti = threadIdx.x >> 5;   // ti 0..7
  #pragma unroll
  for (int j = 0; j < 4; j++){
    int kk = ti + 8 * j;
    tile[kk][tr] = W[(size_t)(kt + kk) * 128 + ct + tr];
  }
  __syncthreads();
  #pragma unroll
  for (int j = 0; j < 4; j++){
    int cc = ti + 8 * j;
    float v = tile[tr][cc];                    // = W[kt+tr][ct+cc]
    u16 hi = f2b(v);
    u16 lo = f2b(v - b2f(hi));
    size_t o = (size_t)mat * 16384 + (size_t)(ct + cc) * 128 + kt + tr;
    WtH[o] = hi;
    WtL[o] = lo;
  }
}

// ---------- node transform via MFMA (bf16x3 split): A[n,128] @ W -> xlb/xrb bf16 ----------
// grid (Mtiles, 2): y=0 -> Wl -> xlb, y=1 -> Wr -> xrb. LDS 54 KB, K staged in halves.
__global__ __launch_bounds__(256) void k_gemm2(
    const float* __restrict__ A,
    const u16* __restrict__ WtH, const u16* __restrict__ WtL,   // [2][128c][128k]
    u16* __restrict__ xlb, u16* __restrict__ xrb, int nrows)
{
  __shared__ u16 sAH[64][72], sAL[64][72];
  __shared__ u16 sWH[128][72], sWL[128][72];
  int t = threadIdx.x, wv = t >> 6, lane = t & 63;
  int col = lane & 15, kg = lane >> 4;
  int r0 = blockIdx.x * 64;
  int mat = blockIdx.y;
  const u16* WHb = WtH + (size_t)mat * 16384;
  const u16* WLb = WtL + (size_t)mat * 16384;

  f32x4 acc[4][2];
  #pragma unroll
  for (int m = 0; m < 4; m++)
    #pragma unroll
    for (int n = 0; n < 2; n++)
      acc[m][n] = (f32x4){0.f, 0.f, 0.f, 0.f};

  int ar = t >> 2, ak = (t & 3) << 4;      // A: row, 16 k per thread
  int wc = t >> 1, wk = (t & 1) << 5;      // W: col, 32 k per thread

  for (int kh = 0; kh < 2; kh++){
    __syncthreads();
    // ---- stage A half (f32 -> hi/lo bf16) ----
    {
      int gr = r0 + ar;
      const float* ap = A + (size_t)gr * 128 + kh * 64 + ak;
      float4 va = {0,0,0,0}, vb = {0,0,0,0}, vc = {0,0,0,0}, vd = {0,0,0,0};
      if (gr < nrows){
        va = *(const float4*)ap; vb = *(const float4*)(ap + 4);
        vc = *(const float4*)(ap + 8); vd = *(const float4*)(ap + 12);
      }
      float fv[16] = { va.x, va.y, va.z, va.w, vb.x, vb.y, vb.z, vb.w,
                       vc.x, vc.y, vc.z, vc.w, vd.x, vd.y, vd.z, vd.w };
      u32 hp[8], lp[8];
      #pragma unroll
      for (int i = 0; i < 8; i++){
        u16 h0 = f2b(fv[2*i]),   h1 = f2b(fv[2*i+1]);
        u16 l0 = f2b(fv[2*i]   - b2f(h0));
        u16 l1 = f2b(fv[2*i+1] - b2f(h1));
        hp[i] = (u32)h0 | ((u32)h1 << 16);
        lp[i] = (u32)l0 | ((u32)l1 << 16);
      }
      *(uint4*)&sAH[ar][ak]     = make_uint4(hp[0], hp[1], hp[2], hp[3]);
      *(uint4*)&sAH[ar][ak + 8] = make_uint4(hp[4], hp[5], hp[6], hp[7]);
      *(uint4*)&sAL[ar][ak]     = make_uint4(lp[0], lp[1], lp[2], lp[3]);
      *(uint4*)&sAL[ar][ak + 8] = make_uint4(lp[4], lp[5], lp[6], lp[7]);
    }
    // ---- stage W half (pre-split bf16 copy) ----
    {
      const u16* gh = WHb + (size_t)wc * 128 + kh * 64 + wk;
      const u16* gl = WLb + (size_t)wc * 128 + kh * 64 + wk;
      uint4 h0 = *(const uint4*)gh, h1 = *(const uint4*)(gh + 8);
      uint4 h2 = *(const uint4*)(gh + 16), h3 = *(const uint4*)(gh + 24);
      uint4 l0 = *(const uint4*)gl, l1 = *(const uint4*)(gl + 8);
      uint4 l2 = *(const uint4*)(gl + 16), l3 = *(const uint4*)(gl + 24);
      *(uint4*)&sWH[wc][wk]      = h0; *(uint4*)&sWH[wc][wk + 8]  = h1;
      *(uint4*)&sWH[wc][wk + 16] = h2; *(uint4*)&sWH[wc][wk + 24] = h3;
      *(uint4*)&sWL[wc][wk]      = l0; *(uint4*)&sWL[wc][wk + 8]  = l1;
      *(uint4*)&sWL[wc][wk + 16] = l2; *(uint4*)&sWL[wc][wk + 24] = l3;
    }
    __syncthreads();
    // ---- compute: per wave 2 N-subtiles x 4 M-subtiles x 2 k-steps x 3 MFMAs ----
    #pragma unroll
    for (int ks = 0; ks < 2; ks++){
      bf16x8 bhi0 = *(const bf16x8*)&sWH[wv*32 + col]     [ks*32 + kg*8];
      bf16x8 bhi1 = *(const bf16x8*)&sWH[wv*32 + 16 + col][ks*32 + kg*8];
      bf16x8 blo0 = *(const bf16x8*)&sWL[wv*32 + col]     [ks*32 + kg*8];
      bf16x8 blo1 = *(const bf16x8*)&sWL[wv*32 + 16 + col][ks*32 + kg*8];
      #pragma unroll
      for (int m = 0; m < 4; m++){
        bf16x8 ahv = *(const bf16x8*)&sAH[m*16 + col][ks*32 + kg*8];
        bf16x8 alv = *(const bf16x8*)&sAL[m*16 + col][ks*32 + kg*8];
        acc[m][0] = __builtin_amdgcn_mfma_f32_16x16x32_bf16(ahv, bhi0, acc[m][0], 0, 0, 0);
        acc[m][0] = __builtin_amdgcn_mfma_f32_16x16x32_bf16(alv, bhi0, acc[m][0], 0, 0, 0);
        acc[m][0] = __builtin_amdgcn_mfma_f32_16x16x32_bf16(ahv, blo0, acc[m][0], 0, 0, 0);
        acc[m][1] = __builtin_amdgcn_mfma_f32_16x16x32_bf16(ahv, bhi1, acc[m][1], 0, 0, 0);
        acc[m][1] = __builtin_amdgcn_mfma_f32_16x16x32_bf16(alv, bhi1, acc[m][1], 0, 0, 0);
        acc[m][1] = __builtin_amdgcn_mfma_f32_16x16x32_bf16(ahv, blo1, acc[m][1], 0, 0, 0);
      }
    }
  }
  // ---- write bf16 out: D layout col=lane&15, row=kg*4+r ----
  u16* ob = mat ? xrb : xlb;
  #pragma unroll
  for (int m = 0; m < 4; m++){
    #pragma unroll
    for (int n = 0; n < 2; n++){
      #pragma unroll
      for (int r = 0; r < 4; r++){
        int row = r0 + m*16 + kg*4 + r;
        int c   = wv*32 + n*16 + col;
        if (row < nrows) ob[(size_t)row * 128 + c] = f2b(acc[m][n][r]);
      }
    }
  }
}

// ---------- edge kernel: MFMA ea@We + LDS bounce + thread-per-edge epilogue ----------
__global__ __launch_bounds__(256) void k_edge(
    const int* __restrict__ ssrc, const int* __restrict__ sdst,
    const u16* __restrict__ ea2,
    const u16* __restrict__ xlb, const u16* __restrict__ xrb,
    const float* __restrict__ We, const float* __restrict__ att,
    float2* __restrict__ pr2, int ntiles, int E)
{
  __shared__ float sD[4][16][136];
  int wv = threadIdx.x >> 6, lane = threadIdx.x & 63;
  int col = lane & 15, kg = lane >> 4;
  int er = lane >> 2, q = lane & 3;

  bf16x8 bw[8];
  #pragma unroll
  for (int c = 0; c < 8; c++)
    #pragma unroll
    for (int j = 0; j < 8; j++)
      bw[c][j] = (short)f2b(We[(kg * 8 + j) * 128 + c * 16 + col]);
  float attq[32];
  #pragma unroll
  for (int i = 0; i < 8; i++){
    float4 a4 = *(const float4*)(att + q * 32 + i * 4);
    attq[4*i] = a4.x; attq[4*i+1] = a4.y; attq[4*i+2] = a4.z; attq[4*i+3] = a4.w;
  }

  int wid0 = blockIdx.x * 4 + wv;
  int nw = gridDim.x * 4;
  for (int t = wid0; t < ntiles; t += nw){
    int e0 = t * 16;
    bf16x8 a = *(const bf16x8*)(ea2 + (size_t)(e0 + col) * 32 + kg * 8);
    #pragma unroll
    for (int c = 0; c < 8; c++){
      f32x4 d = __builtin_amdgcn_mfma_f32_16x16x32_bf16(a, bw[c], (f32x4){0.f,0.f,0.f,0.f}, 0, 0, 0);
      #pragma unroll
      for (int r = 0; r < 4; r++)
        sD[wv][kg * 4 + r][c * 16 + col] = d[r];
    }
    int p = e0 + er;
    int sn = ssrc[p], dn = sdst[p];
    const u16* xj = xlb + (size_t)sn * 128 + q * 32;
    const u16* xi = xrb + (size_t)dn * 128 + q * 32;
    uint4 jq[4], iq[4];
    jq[0] = *(const uint4*)(xj);      jq[1] = *(const uint4*)(xj + 8);
    jq[2] = *(const uint4*)(xj + 16); jq[3] = *(const uint4*)(xj + 24);
    iq[0] = *(const uint4*)(xi);      iq[1] = *(const uint4*)(xi + 8);
    iq[2] = *(const uint4*)(xi + 16); iq[3] = *(const uint4*)(xi + 24);
    const float* drow = &sD[wv][er][q * 32];

    float acc = 0.f;
    #pragma unroll
    for (int k = 0; k < 4; k++){
      float4 d0 = *(const float4*)(drow + k * 8);
      float4 d1 = *(const float4*)(drow + k * 8 + 4);
      u32 jw[4] = { jq[k].x, jq[k].y, jq[k].z, jq[k].w };
      u32 iw[4] = { iq[k].x, iq[k].y, iq[k].z, iq[k].w };
      float dv[8] = { d0.x, d0.y, d0.z, d0.w, d1.x, d1.y, d1.z, d1.w };
      #pragma unroll
      for (int m = 0; m < 4; m++){
        float v0 = dv[2*m]   + bl(jw[m]) + bl(iw[m]);
        float v1 = dv[2*m+1] + bh(jw[m]) + bh(iw[m]);
        v0 = fmaxf(v0, 0.2f * v0);
        v1 = fmaxf(v1, 0.2f * v1);
        acc = fmaf(v0, attq[k*8 + 2*m], acc);
        acc = fmaf(v1, attq[k*8 + 2*m + 1], acc);
      }
    }
    acc += __shfl_xor(acc, 1);
    float other = __shfl_xor(acc, 2);
    if (q == 0 && p < E){
      float l0 = fminf(acc, 80.f), l1 = fminf(other, 80.f);
      pr2[p] = make_float2(__expf(l0), __expf(l1));
    }
  }
}

// ---------- per-node reduce, 8-deep NAMED-scalar pipeline, bf16 gathers ----------
template<int RELU>
__global__ __launch_bounds__(256) void k_seg2(
    const int* __restrict__ seg, const int* __restrict__ ssrc,
    const float2* __restrict__ pr2,
    const u16* __restrict__ xlb, const float* __restrict__ bias,
    float* __restrict__ out, int N)
{
  int wid  = blockIdx.x * 4 + (threadIdx.x >> 6);
  int lane = threadIdx.x & 63;
  if (wid >= N) return;
  int c0 = lane * 2, head = lane >> 5;

  int p0 = seg[wid], p1 = seg[wid + 1];
  float2 bv = *(const float2*)(bias + c0);
  float s = 0.f, o0 = 0.f, o1 = 0.f;

  for (int p = p0; p < p1; p += 8){
#define STAGE(K) \
    int i##K = (p + K < p1) ? (p + K) : (p1 - 1); \
    int sn##K = ssrc[i##K]; \
    float2 q##K = pr2[i##K]; \
    u32 xv##K = *(const u32*)(xlb + (size_t)sn##K * 128 + c0);
    STAGE(0) STAGE(1) STAGE(2) STAGE(3) STAGE(4) STAGE(5) STAGE(6) STAGE(7)
#undef STAGE
#define ACCUM(K) { \
    float e##K = head ? q##K.y : q##K.x; \
    if (p + K >= p1) e##K = 0.f; \
    s += e##K; \
    o0 = fmaf(e##K, bl(xv##K), o0); \
    o1 = fmaf(e##K, bh(xv##K), o1); }
    ACCUM(0) ACCUM(1) ACCUM(2) ACCUM(3) ACCUM(4) ACCUM(5) ACCUM(6) ACCUM(7)
#undef ACCUM
  }
  float inv = 1.0f / (s + 1e-16f);
  float r0 = fmaf(o0, inv, bv.x);
  float r1 = fmaf(o1, inv, bv.y);
  if (RELU){ r0 = fmaxf(r0, 0.f); r1 = fmaxf(r1, 0.f); }
  *(float2*)(out + (size_t)wid * 128 + c0) = make_float2(r0, r1);
}

// ---------- launch ----------
extern "C" void kernel_launch(void* const* d_in, const int* in_sizes, int n_in,
                              void* d_out, int out_size, void* d_ws, size_t ws_size,
                              hipStream_t stream)
{
  const float* x     = (const float*)d_in[0];
  const int*   ei    = (const int*)  d_in[1];
  const float* eattr = (const float*)d_in[2];
  const float* Wp[3][5];
  for (int l = 0; l < 3; l++)
    for (int j = 0; j < 5; j++)
      Wp[l][j] = (const float*)d_in[3 + l * 5 + j];

  int N = in_sizes[0] / 128;
  int E = in_sizes[2] / 32;

  char* w = (char*)d_ws;
  auto alloc = [&](size_t bytes) -> char* {
    char* p = w; w += (bytes + 255) & ~(size_t)255; return p;
  };
  float* xr   = (float*)alloc((size_t)N * 128 * 4);   // inter-layer h buffer
  u16*   xlb  = (u16*)  alloc((size_t)N * 128 * 2);
  u16*   xrb  = (u16*)  alloc((size_t)N * 128 * 2);
  u16*   ea2  = (u16*)  alloc((size_t)(E + 64) * 32 * 2);
  float2* prb = (float2*)alloc((size_t)E * 8);
  u16*   WtH  = (u16*)  alloc((size_t)6 * 16384 * 2);
  u16*   WtL  = (u16*)  alloc((size_t)6 * 16384 * 2);
  int* srcA   = (int*)alloc((size_t)E * 4);
  int* dstA   = (int*)alloc((size_t)E * 4);
  int* ssrc   = (int*)alloc((size_t)(E + 64) * 4);
  int* sdst   = (int*)alloc((size_t)(E + 64) * 4);
  int* seid   = (int*)alloc((size_t)E * 4);
  int* deg    = (int*)alloc((size_t)N * 4);
  int* cur    = (int*)alloc((size_t)N * 4);
  int* seg    = (int*)alloc((size_t)(N + 1) * 4);
  u32* flag   = (u32*)alloc(256);

  hipMemsetAsync(deg,  0, (size_t)N * 4, stream);
  hipMemsetAsync(cur,  0, (size_t)N * 4, stream);
  hipMemsetAsync(flag, 0, 4, stream);
  hipMemsetAsync(ssrc + E, 0, 64 * 4, stream);
  hipMemsetAsync(sdst + E, 0, 64 * 4, stream);

  int ndet = (E < 16384) ? E : 16384;
  k_detect<<<(ndet + 255) / 256, 256, 0, stream>>>((const u32*)ei, ndet, flag);
  int gE = (E + 255) / 256;
  k_convhist<<<gE, 256, 0, stream>>>(ei, srcA, dstA, deg, E, flag);
  k_scan<<<1, 1024, 0, stream>>>(deg, seg, N);
  k_scatter<<<gE, 256, 0, stream>>>(srcA, dstA, seg, cur, ssrc, sdst, seid, E);
  k_sorte<<<gE, 256, 0, stream>>>(seid, eattr, ea2, E);
  dim3 gp(4, 4, 6);
  k_prepw<<<gp, 256, 0, stream>>>(Wp[0][0], Wp[0][1], Wp[1][0], Wp[1][1], Wp[2][0], Wp[2][1], WtH, WtL);

  int gS = (N + 3) / 4;
  int ntiles = (E + 15) / 16;
  int gEdge = (ntiles + 3) / 4; if (gEdge > 2048) gEdge = 2048;
  dim3 gG2((N + 63) / 64, 2);

  const float* hin = x;
  for (int l = 0; l < 3; l++){
    k_gemm2<<<gG2, 256, 0, stream>>>(hin, WtH + (size_t)l * 2 * 16384, WtL + (size_t)l * 2 * 16384, xlb, xrb, N);
    k_edge<<<gEdge, 256, 0, stream>>>(ssrc, sdst, ea2, xlb, xrb, Wp[l][2], Wp[l][3], prb, ntiles, E);
    float* outp = (l == 2) ? (float*)d_out : xr;
    if (l == 2) k_seg2<0><<<gS, 256, 0, stream>>>(seg, ssrc, prb, xlb, Wp[l][4], outp, N);
    else        k_seg2<1><<<gS, 256, 0, stream>>>(seg, ssrc, prb, xlb, Wp[l][4], outp, N);
    hin = xr;
  }
}